// Round 1
// baseline (516.218 us; speedup 1.0000x reference)
//
#include <hip/hip_runtime.h>
#include <math.h>

namespace {

constexpr int L   = 200;
constexpr int E   = 64;
constexpr int H1N = 80;
constexpr int H2N = 40;

__global__ __launch_bounds__(256, 2)
void attn_fused(const float* __restrict__ q,
                const float* __restrict__ kmat,
                const float* __restrict__ vmat,
                const void* __restrict__ mask,
                const float* __restrict__ W1,
                const float* __restrict__ b1,
                const float* __restrict__ W2,
                const float* __restrict__ b2,
                const float* __restrict__ Wf,
                const float* __restrict__ bfp,
                float* __restrict__ out)
{
    const int b    = blockIdx.x;
    const int tid  = threadIdx.x;
    const int lane = tid & 63;
    const int wv   = tid >> 6;

    // LDS ~38.6 KB -> 2 blocks/CU fits easily (160 KiB/CU)
    __shared__ float q_s[E];
    __shared__ float Mt[H1N][68];      // [j][i], pad 68 (16B-aligned rows for b128)
    __shared__ float cq_s[H1N];
    __shared__ float W2_s[H1N][H2N];   // [j][n], n contiguous
    __shared__ float b2_s[H2N];
    __shared__ float Wf_s[H2N];
    __shared__ float score_s[256];
    __shared__ float red_s[8];
    __shared__ float part_s[4][E];
    __shared__ int   flag_s;           // 1 if mask marshaled as int32, 0 if bytes

    // ---- Phase 0a: q load + mask-dtype sniff ----
    if (tid < E) q_s[tid] = q[(size_t)b * E + tid];
    if (tid == 0) {
        // int32 storage of 0/1 values => every byte at offset %4 != 0 is zero.
        // byte-bool storage => those are random 0/1 bits (P[all 192 zero] ~ 2^-192).
        const unsigned char* mb = (const unsigned char*)mask;
        int isI32 = 1;
        for (int t = 0; t < 256; ++t)
            if ((t & 3) && mb[t]) { isI32 = 0; break; }
        flag_s = isI32;
    }
    __syncthreads();

    // ---- Phase 0b: per-batch folded weights ----
    // h1[j] = cq[j] + sum_i k_i * M[i][j],
    //   cq[j] = b1[j] + sum_i q_i*(W1[i,j] + W1[128+i,j])
    //   M[i][j] = (W1[64+i,j] - W1[128+i,j]) + q_i * W1[192+i,j]
    for (int idx = tid; idx < H1N * H2N; idx += 256)
        W2_s[idx / H2N][idx % H2N] = W2[idx];
    if (tid < H2N) { b2_s[tid] = b2[tid]; Wf_s[tid] = Wf[tid]; }
    if (tid < H1N) {
        float s = b1[tid];
        #pragma unroll 8
        for (int i = 0; i < E; ++i)
            s += q_s[i] * (W1[i * H1N + tid] + W1[(2 * E + i) * H1N + tid]);
        cq_s[tid] = s;
    }
    for (int idx = tid; idx < E * H1N; idx += 256) {
        const int i = idx / H1N;
        const int j = idx - i * H1N;
        Mt[j][i] = (W1[(E + i) * H1N + j] - W1[(2 * E + i) * H1N + j])
                 + q_s[i] * W1[(3 * E + i) * H1N + j];
    }
    __syncthreads();

    // ---- Phase 1: one thread per l computes its logit ----
    const int l = (tid < L) ? tid : 0;

    float kreg[E];
    {
        const float4* kp = (const float4*)(kmat + ((size_t)b * L + l) * E);
        #pragma unroll
        for (int c = 0; c < E / 4; ++c) {
            const float4 t = kp[c];
            kreg[4 * c + 0] = t.x;
            kreg[4 * c + 1] = t.y;
            kreg[4 * c + 2] = t.z;
            kreg[4 * c + 3] = t.w;
        }
    }

    float h2r[H2N];
    #pragma unroll
    for (int n = 0; n < H2N; ++n) h2r[n] = b2_s[n];

    for (int j = 0; j < H1N; ++j) {
        float a0 = 0.f, a1 = 0.f, a2 = 0.f, a3 = 0.f;
        #pragma unroll
        for (int i = 0; i < E; i += 4) {        // Mt reads: wave-broadcast b128
            a0 += kreg[i + 0] * Mt[j][i + 0];
            a1 += kreg[i + 1] * Mt[j][i + 1];
            a2 += kreg[i + 2] * Mt[j][i + 2];
            a3 += kreg[i + 3] * Mt[j][i + 3];
        }
        const float h1j = cq_s[j] + ((a0 + a1) + (a2 + a3));
        #pragma unroll
        for (int n = 0; n < H2N; ++n)           // stream h1 straight into h2
            h2r[n] += h1j * W2_s[j][n];
    }

    float logit = bfp[0];
    #pragma unroll
    for (int n = 0; n < H2N; ++n) {
        const float s = 1.0f / (1.0f + __expf(-h2r[n]));
        logit += s * Wf_s[n];
    }

    {
        const size_t mi = (size_t)b * L + l;
        const int mv = flag_s ? ((const int*)mask)[mi]
                              : (int)((const unsigned char*)mask)[mi];
        if (mv != 0 || tid >= L) logit = -INFINITY;
    }

    // ---- Phase 2: masked softmax over L (block-wide) ----
    float m = logit;
    #pragma unroll
    for (int off = 32; off > 0; off >>= 1)
        m = fmaxf(m, __shfl_xor(m, off));
    if (lane == 0) red_s[wv] = m;
    __syncthreads();
    const float gmax = fmaxf(fmaxf(red_s[0], red_s[1]), fmaxf(red_s[2], red_s[3]));

    const float e = __expf(logit - gmax);   // exp(-inf) = 0 for masked / idle
    score_s[tid] = e;
    float ssum = e;
    #pragma unroll
    for (int off = 32; off > 0; off >>= 1)
        ssum += __shfl_xor(ssum, off);
    if (lane == 0) red_s[4 + wv] = ssum;
    __syncthreads();
    const float inv = 1.0f / (red_s[4] + red_s[5] + red_s[6] + red_s[7]);

    // ---- Phase 3: out[e] = sum_l score_l * v[b,l,e]  (coalesced v reads) ----
    float pacc = 0.f;
    #pragma unroll 5
    for (int ll = wv; ll < L; ll += 4)
        pacc += score_s[ll] * vmat[((size_t)b * L + ll) * E + lane];
    part_s[wv][lane] = pacc;
    __syncthreads();
    if (wv == 0) {
        const float o = (part_s[0][lane] + part_s[1][lane]
                       + part_s[2][lane] + part_s[3][lane]) * inv;
        out[(size_t)b * E + lane] = o;
    }
}

} // namespace

extern "C" void kernel_launch(void* const* d_in, const int* in_sizes, int n_in,
                              void* d_out, int out_size, void* d_ws, size_t ws_size,
                              hipStream_t stream) {
    const float* q  = (const float*)d_in[0];
    const float* k  = (const float*)d_in[1];
    const float* v  = (const float*)d_in[2];
    const void*  mk = d_in[3];
    const float* W1 = (const float*)d_in[4];
    const float* b1 = (const float*)d_in[5];
    const float* W2 = (const float*)d_in[6];
    const float* b2 = (const float*)d_in[7];
    const float* Wf = (const float*)d_in[8];
    const float* bf = (const float*)d_in[9];
    float* out = (float*)d_out;

    const int B = in_sizes[0] / E;   // 4096
    attn_fused<<<B, 256, 0, stream>>>(q, k, v, mk, W1, b1, W2, b2, Wf, bf, out);
}

// Round 2
// 197.586 us; speedup vs baseline: 2.6126x; 2.6126x over previous
//
#include <hip/hip_runtime.h>
#include <math.h>

namespace {

constexpr int L   = 200;
constexpr int E   = 64;
constexpr int H1N = 80;
constexpr int H2N = 40;
constexpr int MT_PAD = 72;    // Mt row stride in ushort (144 B, 16B-aligned, bank-friendly)
constexpr int W2_PAD = 104;   // W2t / H1t row stride in ushort (208 B)

using short8 = __attribute__((ext_vector_type(8))) short;
using f32x4  = __attribute__((ext_vector_type(4))) float;

__device__ inline unsigned short f2bf(float f) {
    union { float f; unsigned u; } x{f};
    unsigned r = x.u + 0x7fffu + ((x.u >> 16) & 1u);   // round-to-nearest-even
    return (unsigned short)(r >> 16);
}

__global__ __launch_bounds__(256, 2)
void attn_fused(const float* __restrict__ q,
                const float* __restrict__ kmat,
                const float* __restrict__ vmat,
                const void* __restrict__ mask,
                const float* __restrict__ W1,
                const float* __restrict__ b1,
                const float* __restrict__ W2,
                const float* __restrict__ b2,
                const float* __restrict__ Wf,
                const float* __restrict__ bfp,
                float* __restrict__ out)
{
    const int b    = blockIdx.x;
    const int tid  = threadIdx.x;
    const int lane = tid & 63;
    const int wv   = tid >> 6;
    const int g    = lane >> 4;    // 16-lane group 0..3
    const int col  = lane & 15;

    __shared__ float q_s[E];
    __shared__ unsigned short Mt[H1N][MT_PAD];     // Mt[j][i] = M[i][j], bf16
    __shared__ float cq_s[H1N];
    __shared__ unsigned short W2t[48][W2_PAD];     // W2t[n][j] = W2[j][n], bf16, zero-padded
    __shared__ float b2_s[48];
    __shared__ float Wf_s[48];
    __shared__ unsigned short H1t[4][16][W2_PAD];  // per-wave H1 tile, bf16
    __shared__ float score_s[256];
    __shared__ float red_s[8];
    __shared__ float part_s[4][E];
    __shared__ int   flag_s;

    // ---- Phase 0a: q load + mask-dtype sniff ----
    if (tid < E) q_s[tid] = q[(size_t)b * E + tid];
    if (tid == 0) {
        const unsigned char* mb = (const unsigned char*)mask;
        int isI32 = 1;
        for (int t = 0; t < 256; ++t)
            if ((t & 3) && mb[t]) { isI32 = 0; break; }
        flag_s = isI32;
    }
    __syncthreads();

    // ---- Phase 0b: per-batch folded weights ----
    // h1[j] = cq[j] + sum_i k_i * M[i][j]
    //   cq[j] = b1[j] + sum_i q_i*(W1[i,j] + W1[2E+i,j])
    //   M[i][j] = (W1[E+i,j] - W1[2E+i,j]) + q_i * W1[3E+i,j]
    if (tid < H1N) {
        float s = b1[tid];
        #pragma unroll 8
        for (int i = 0; i < E; ++i)
            s += q_s[i] * (W1[i * H1N + tid] + W1[(2 * E + i) * H1N + tid]);
        cq_s[tid] = s;
    }
    for (int idx = tid; idx < E * H1N; idx += 256) {
        const int i = idx / H1N;
        const int j = idx - i * H1N;
        const float m = (W1[(E + i) * H1N + j] - W1[(2 * E + i) * H1N + j])
                      + q_s[i] * W1[(3 * E + i) * H1N + j];
        Mt[j][i] = f2bf(m);
    }
    for (int idx = tid; idx < 96 * 48; idx += 256) {
        const int j = idx / 48;
        const int n = idx - j * 48;
        const float w = (j < H1N && n < H2N) ? W2[j * H2N + n] : 0.f;
        W2t[n][j] = f2bf(w);
    }
    if (tid < 48) {
        b2_s[tid] = (tid < H2N) ? b2[tid] : 0.f;
        Wf_s[tid] = (tid < H2N) ? Wf[tid] : 0.f;
    }
    // zero H1t pad cols 80..95 (K-padding for GEMM2)
    for (int idx = tid; idx < 4 * 16 * 16; idx += 256) {
        const int w_ = idx >> 8;
        const int i  = (idx >> 4) & 15;
        const int c  = idx & 15;
        H1t[w_][i][80 + c] = 0;
    }
    const float bf0 = bfp[0];
    __syncthreads();

    // ---- Phase 1: MFMA MLP per 16-row tile ----
    // B-fragments (reused across all row tiles of this wave)
    short8 b1f[5][2];
    #pragma unroll
    for (int nt = 0; nt < 5; ++nt)
        #pragma unroll
        for (int ks = 0; ks < 2; ++ks)
            b1f[nt][ks] = *(const short8*)&Mt[nt * 16 + col][ks * 32 + g * 8];

    short8 b2f[3][3];
    #pragma unroll
    for (int nt = 0; nt < 3; ++nt)
        #pragma unroll
        for (int ks = 0; ks < 3; ++ks)
            b2f[nt][ks] = *(const short8*)&W2t[nt * 16 + col][ks * 32 + g * 8];

    for (int rt = 0; rt < 4; ++rt) {
        const int t = wv + 4 * rt;     // tiles 0..12 (13 tiles cover 208 >= 200 rows)
        if (t < 13) {
            const int row = min(16 * t + col, L - 1);
            const float* kp = kmat + ((size_t)b * L + row) * E;

            short8 a1f[2];
            #pragma unroll
            for (int ks = 0; ks < 2; ++ks) {
                const float4 u0 = *(const float4*)(kp + ks * 32 + g * 8);
                const float4 u1 = *(const float4*)(kp + ks * 32 + g * 8 + 4);
                short8 a;
                a[0] = f2bf(u0.x); a[1] = f2bf(u0.y); a[2] = f2bf(u0.z); a[3] = f2bf(u0.w);
                a[4] = f2bf(u1.x); a[5] = f2bf(u1.y); a[6] = f2bf(u1.z); a[7] = f2bf(u1.w);
                a1f[ks] = a;
            }

            f32x4 acc1[5];
            #pragma unroll
            for (int nt = 0; nt < 5; ++nt) acc1[nt] = f32x4{0.f, 0.f, 0.f, 0.f};
            #pragma unroll
            for (int nt = 0; nt < 5; ++nt)
                #pragma unroll
                for (int ks = 0; ks < 2; ++ks)
                    acc1[nt] = __builtin_amdgcn_mfma_f32_16x16x32_bf16(
                        a1f[ks], b1f[nt][ks], acc1[nt], 0, 0, 0);

            // H1 = acc1 + cq  -> bf16 -> per-wave LDS tile (D layout: col=lane&15, row=4g+r)
            #pragma unroll
            for (int nt = 0; nt < 5; ++nt)
                #pragma unroll
                for (int r = 0; r < 4; ++r)
                    H1t[wv][4 * g + r][nt * 16 + col] =
                        f2bf(acc1[nt][r] + cq_s[nt * 16 + col]);

            short8 a2f[3];
            #pragma unroll
            for (int ks = 0; ks < 3; ++ks)
                a2f[ks] = *(const short8*)&H1t[wv][col][ks * 32 + g * 8];

            f32x4 acc2[3];
            #pragma unroll
            for (int nt = 0; nt < 3; ++nt) acc2[nt] = f32x4{0.f, 0.f, 0.f, 0.f};
            #pragma unroll
            for (int nt = 0; nt < 3; ++nt)
                #pragma unroll
                for (int ks = 0; ks < 3; ++ks)
                    acc2[nt] = __builtin_amdgcn_mfma_f32_16x16x32_bf16(
                        a2f[ks], b2f[nt][ks], acc2[nt], 0, 0, 0);

            // sigmoid + logit partial (lane holds col n = nt*16+col, rows 4g+r)
            float pl[4] = {0.f, 0.f, 0.f, 0.f};
            #pragma unroll
            for (int nt = 0; nt < 3; ++nt) {
                const float b2v = b2_s[nt * 16 + col];
                const float wfv = Wf_s[nt * 16 + col];
                #pragma unroll
                for (int r = 0; r < 4; ++r) {
                    const float h2 = acc2[nt][r] + b2v;
                    const float s  = 1.0f / (1.0f + __expf(-h2));
                    pl[r] += s * wfv;
                }
            }
            #pragma unroll
            for (int r = 0; r < 4; ++r) {
                #pragma unroll
                for (int off = 1; off < 16; off <<= 1)
                    pl[r] += __shfl_xor(pl[r], off);
            }
            if (col == 0) {
                #pragma unroll
                for (int r = 0; r < 4; ++r)
                    score_s[16 * t + 4 * g + r] = bf0 + pl[r];
            }
        }
    }
    __syncthreads();

    // ---- Phase 2: masked softmax over L ----
    float logit = -INFINITY;
    if (tid < L) {
        logit = score_s[tid];
        const size_t mi = (size_t)b * L + tid;
        const int mv = flag_s ? ((const int*)mask)[mi]
                              : (int)((const unsigned char*)mask)[mi];
        if (mv != 0) logit = -INFINITY;
    }

    float m = logit;
    #pragma unroll
    for (int off = 32; off > 0; off >>= 1)
        m = fmaxf(m, __shfl_xor(m, off));
    if (lane == 0) red_s[wv] = m;
    __syncthreads();
    const float gmax = fmaxf(fmaxf(red_s[0], red_s[1]), fmaxf(red_s[2], red_s[3]));

    const float e = __expf(logit - gmax);
    score_s[tid] = e;
    float ssum = e;
    #pragma unroll
    for (int off = 32; off > 0; off >>= 1)
        ssum += __shfl_xor(ssum, off);
    if (lane == 0) red_s[4 + wv] = ssum;
    __syncthreads();
    const float inv = 1.0f / (red_s[4] + red_s[5] + red_s[6] + red_s[7]);

    // ---- Phase 3: out[e] = sum_l score_l * v[b,l,e] ----
    float pacc = 0.f;
    #pragma unroll 5
    for (int ll = wv; ll < L; ll += 4)
        pacc += score_s[ll] * vmat[((size_t)b * L + ll) * E + lane];
    part_s[wv][lane] = pacc;
    __syncthreads();
    if (wv == 0) {
        const float o = (part_s[0][lane] + part_s[1][lane]
                       + part_s[2][lane] + part_s[3][lane]) * inv;
        out[(size_t)b * E + lane] = o;
    }
}

} // namespace

extern "C" void kernel_launch(void* const* d_in, const int* in_sizes, int n_in,
                              void* d_out, int out_size, void* d_ws, size_t ws_size,
                              hipStream_t stream) {
    const float* q  = (const float*)d_in[0];
    const float* k  = (const float*)d_in[1];
    const float* v  = (const float*)d_in[2];
    const void*  mk = d_in[3];
    const float* W1 = (const float*)d_in[4];
    const float* b1 = (const float*)d_in[5];
    const float* W2 = (const float*)d_in[6];
    const float* b2 = (const float*)d_in[7];
    const float* Wf = (const float*)d_in[8];
    const float* bf = (const float*)d_in[9];
    float* out = (float*)d_out;

    const int B = in_sizes[0] / E;   // 4096
    attn_fused<<<B, 256, 0, stream>>>(q, k, v, mk, W1, b1, W2, b2, Wf, bf, out);
}

// Round 3
// 170.730 us; speedup vs baseline: 3.0236x; 1.1573x over previous
//
#include <hip/hip_runtime.h>
#include <math.h>

namespace {

constexpr int L   = 200;
constexpr int E   = 64;
constexpr int H1N = 80;
constexpr int H2N = 40;

using short8 = __attribute__((ext_vector_type(8))) short;
using f32x4  = __attribute__((ext_vector_type(4))) float;

__device__ inline unsigned short f2bf(float f) {
    union { float f; unsigned u; } x{f};
    unsigned r = x.u + 0x7fffu + ((x.u >> 16) & 1u);   // RNE
    return (unsigned short)(r >> 16);
}

// ---- workspace layout (bytes) ----
// [0,      20480)  Afrag  f32 [640*8]   (W1_k - W1_d, b1f fragment order)
// [20480,  40960)  Cfrag  f32 [640*8]   (W1_p,        b1f fragment order)
// [40960,  50176)  W2f    bf16[576*8]   (b2f fragment order, zero-padded)
// [50176,  50176+B*80*4)  cq_all f32
constexpr int WS_AF  = 0;
constexpr int WS_CF  = 20480;
constexpr int WS_W2F = 40960;
constexpr int WS_CQ  = 50176;

// K0a: batch-independent weight packing. grid = 5 blocks x 256.
__global__ void k0_pack(const float* __restrict__ W1,
                        const float* __restrict__ W2,
                        float* __restrict__ Af,
                        float* __restrict__ Cf,
                        unsigned short* __restrict__ W2f)
{
    const int id = blockIdx.x * 256 + threadIdx.x;   // 0..1279, tasks 0..1215
    if (id < 640) {
        const int u  = id;
        const int c  = u >> 6, ln = u & 63;
        const int nt = c >> 1, ks = c & 1;
        const int j  = nt * 16 + (ln & 15);
        const int i0 = ks * 32 + (ln >> 4) * 8;
        #pragma unroll
        for (int e = 0; e < 8; ++e) {
            const int i = i0 + e;
            Af[u * 8 + e] = W1[(E + i) * H1N + j] - W1[(2 * E + i) * H1N + j];
            Cf[u * 8 + e] = W1[(3 * E + i) * H1N + j];
        }
    } else if (id < 640 + 576) {
        const int u   = id - 640;
        const int c   = u >> 6, ln = u & 63;
        const int nt2 = c / 3, ks2 = c % 3;
        const int n   = nt2 * 16 + (ln & 15);
        const int j0  = ks2 * 32 + (ln >> 4) * 8;
        #pragma unroll
        for (int e = 0; e < 8; ++e) {
            const int j = j0 + e;
            W2f[u * 8 + e] = (j < H1N && n < H2N) ? f2bf(W2[j * H2N + n])
                                                  : (unsigned short)0;
        }
    }
}

// K0b: cq_all[b][j] = b1[j] + sum_i q[b,i]*(W1[i,j] + W1[2E+i,j])
__global__ void k0_cq(const float* __restrict__ q,
                      const float* __restrict__ W1,
                      const float* __restrict__ b1,
                      float* __restrict__ cq_all, int B)
{
    const int id = blockIdx.x * 256 + threadIdx.x;
    if (id >= B * H1N) return;
    const int b = id / H1N;
    const int j = id - b * H1N;
    const float* qb = q + (size_t)b * E;
    float s = b1[j];
    #pragma unroll 8
    for (int i = 0; i < E; ++i)
        s += qb[i] * (W1[i * H1N + j] + W1[(2 * E + i) * H1N + j]);
    cq_all[id] = s;
}

__global__ __launch_bounds__(256, 6)
void attn_main(const float* __restrict__ q,
               const float* __restrict__ kmat,
               const float* __restrict__ vmat,
               const void* __restrict__ mask,
               const float* __restrict__ b2,
               const float* __restrict__ Wf,
               const float* __restrict__ bfp,
               const float* __restrict__ Af,
               const float* __restrict__ Cf,
               const unsigned short* __restrict__ W2f,
               const float* __restrict__ cq_all,
               float* __restrict__ out)
{
    const int b    = blockIdx.x;
    const int tid  = threadIdx.x;
    const int lane = tid & 63;
    const int wv   = tid >> 6;
    const int g    = lane >> 4;
    const int col  = lane & 15;

    __shared__ float q_s[E];
    __shared__ unsigned short MtfL[640 * 8];      // 10240 B, b1f fragment order
    __shared__ unsigned short H1t[4][16][104];    // 13312 B
    __shared__ float score_s[256];
    __shared__ float red_s[8];
    __shared__ float part_s[4][E];
    __shared__ int   flag_s;

    if (tid < E) q_s[tid] = q[(size_t)b * E + tid];
    if (tid == 0) {
        const unsigned char* mb = (const unsigned char*)mask;
        int isI32 = 1;
        for (int t = 0; t < 256; ++t)
            if ((t & 3) && mb[t]) { isI32 = 0; break; }
        flag_s = isI32;
    }
    // per-wave H1t K-pad zero (cols 80..95)
    *(unsigned long long*)&H1t[wv][lane & 15][80 + (lane >> 4) * 4] = 0ULL;
    __syncthreads();

    // ---- fold Mtf = bf16(A + q*C) into LDS (fragment order) ----
    for (int u = tid; u < 640; u += 256) {
        const float4 a0 = *(const float4*)(Af + u * 8);
        const float4 a1 = *(const float4*)(Af + u * 8 + 4);
        const float4 c0 = *(const float4*)(Cf + u * 8);
        const float4 c1 = *(const float4*)(Cf + u * 8 + 4);
        const int cc = u >> 6, ln = u & 63;
        const int i0 = (cc & 1) * 32 + (ln >> 4) * 8;
        const float* qp = q_s + i0;
        short8 h;
        h[0] = (short)f2bf(a0.x + qp[0] * c0.x);
        h[1] = (short)f2bf(a0.y + qp[1] * c0.y);
        h[2] = (short)f2bf(a0.z + qp[2] * c0.z);
        h[3] = (short)f2bf(a0.w + qp[3] * c0.w);
        h[4] = (short)f2bf(a1.x + qp[4] * c1.x);
        h[5] = (short)f2bf(a1.y + qp[5] * c1.y);
        h[6] = (short)f2bf(a1.z + qp[6] * c1.z);
        h[7] = (short)f2bf(a1.w + qp[7] * c1.w);
        *(short8*)&MtfL[u * 8] = h;
    }
    __syncthreads();

    // ---- per-lane constants ----
    float cqr[5];
    #pragma unroll
    for (int nt = 0; nt < 5; ++nt)
        cqr[nt] = cq_all[(size_t)b * H1N + nt * 16 + col];
    float b2r[3], wfr[3];
    #pragma unroll
    for (int nt2 = 0; nt2 < 3; ++nt2) {
        const int nc = nt2 * 16 + col;
        b2r[nt2] = (nc < H2N) ? b2[nc] : 0.f;
        wfr[nt2] = (nc < H2N) ? Wf[nc] : 0.f;
    }
    const float bf0 = bfp[0];

    // ---- MLP per 16-row tile ----
    for (int rt = 0; rt < 4; ++rt) {
        const int t = wv + 4 * rt;
        if (t < 13) {
            const int row = min(16 * t + col, L - 1);
            const float* kp = kmat + ((size_t)b * L + row) * E;

            short8 a1f[2];
            #pragma unroll
            for (int ks = 0; ks < 2; ++ks) {
                const float4 u0 = *(const float4*)(kp + ks * 32 + g * 8);
                const float4 u1 = *(const float4*)(kp + ks * 32 + g * 8 + 4);
                short8 a;
                a[0] = f2bf(u0.x); a[1] = f2bf(u0.y); a[2] = f2bf(u0.z); a[3] = f2bf(u0.w);
                a[4] = f2bf(u1.x); a[5] = f2bf(u1.y); a[6] = f2bf(u1.z); a[7] = f2bf(u1.w);
                a1f[ks] = a;
            }

            f32x4 acc1[5];
            #pragma unroll
            for (int nt = 0; nt < 5; ++nt) acc1[nt] = f32x4{0.f, 0.f, 0.f, 0.f};
            #pragma unroll
            for (int nt = 0; nt < 5; ++nt)
                #pragma unroll
                for (int ks = 0; ks < 2; ++ks) {
                    const short8 b1f = *(const short8*)&MtfL[((nt * 2 + ks) * 64 + lane) * 8];
                    acc1[nt] = __builtin_amdgcn_mfma_f32_16x16x32_bf16(
                        a1f[ks], b1f, acc1[nt], 0, 0, 0);
                }

            #pragma unroll
            for (int nt = 0; nt < 5; ++nt)
                #pragma unroll
                for (int r = 0; r < 4; ++r)
                    H1t[wv][4 * g + r][nt * 16 + col] = f2bf(acc1[nt][r] + cqr[nt]);

            short8 a2f[3];
            #pragma unroll
            for (int ks2 = 0; ks2 < 3; ++ks2)
                a2f[ks2] = *(const short8*)&H1t[wv][col][ks2 * 32 + g * 8];

            f32x4 acc2[3];
            #pragma unroll
            for (int nt2 = 0; nt2 < 3; ++nt2) acc2[nt2] = f32x4{0.f, 0.f, 0.f, 0.f};
            #pragma unroll
            for (int nt2 = 0; nt2 < 3; ++nt2)
                #pragma unroll
                for (int ks2 = 0; ks2 < 3; ++ks2) {
                    const short8 b2f = *(const short8*)&W2f[((nt2 * 3 + ks2) * 64 + lane) * 8];
                    acc2[nt2] = __builtin_amdgcn_mfma_f32_16x16x32_bf16(
                        a2f[ks2], b2f, acc2[nt2], 0, 0, 0);
                }

            float pl[4] = {0.f, 0.f, 0.f, 0.f};
            #pragma unroll
            for (int nt2 = 0; nt2 < 3; ++nt2) {
                #pragma unroll
                for (int r = 0; r < 4; ++r) {
                    const float h2 = acc2[nt2][r] + b2r[nt2];
                    const float s  = 1.0f / (1.0f + __expf(-h2));
                    pl[r] += s * wfr[nt2];
                }
            }
            #pragma unroll
            for (int r = 0; r < 4; ++r) {
                #pragma unroll
                for (int off = 1; off < 16; off <<= 1)
                    pl[r] += __shfl_xor(pl[r], off);
            }
            if (col == 0) {
                #pragma unroll
                for (int r = 0; r < 4; ++r)
                    score_s[16 * t + 4 * g + r] = bf0 + pl[r];
            }
        }
    }
    __syncthreads();

    // ---- masked softmax over L ----
    float logit = -INFINITY;
    if (tid < L) {
        logit = score_s[tid];
        const size_t mi = (size_t)b * L + tid;
        const int mv = flag_s ? ((const int*)mask)[mi]
                              : (int)((const unsigned char*)mask)[mi];
        if (mv != 0) logit = -INFINITY;
    }

    float m = logit;
    #pragma unroll
    for (int off = 32; off > 0; off >>= 1)
        m = fmaxf(m, __shfl_xor(m, off));
    if (lane == 0) red_s[wv] = m;
    __syncthreads();
    const float gmax = fmaxf(fmaxf(red_s[0], red_s[1]), fmaxf(red_s[2], red_s[3]));

    const float e = __expf(logit - gmax);
    score_s[tid] = e;
    float ssum = e;
    #pragma unroll
    for (int off = 32; off > 0; off >>= 1)
        ssum += __shfl_xor(ssum, off);
    if (lane == 0) red_s[4 + wv] = ssum;
    __syncthreads();
    const float inv = 1.0f / (red_s[4] + red_s[5] + red_s[6] + red_s[7]);

    // ---- out[e] = sum_l score_l * v[b,l,e] ----
    float pacc = 0.f;
    #pragma unroll 5
    for (int ll = wv; ll < L; ll += 4)
        pacc += score_s[ll] * vmat[((size_t)b * L + ll) * E + lane];
    part_s[wv][lane] = pacc;
    __syncthreads();
    if (wv == 0) {
        const float o = (part_s[0][lane] + part_s[1][lane]
                       + part_s[2][lane] + part_s[3][lane]) * inv;
        out[(size_t)b * E + lane] = o;
    }
}

} // namespace

extern "C" void kernel_launch(void* const* d_in, const int* in_sizes, int n_in,
                              void* d_out, int out_size, void* d_ws, size_t ws_size,
                              hipStream_t stream) {
    const float* q  = (const float*)d_in[0];
    const float* k  = (const float*)d_in[1];
    const float* v  = (const float*)d_in[2];
    const void*  mk = d_in[3];
    const float* W1 = (const float*)d_in[4];
    const float* b1 = (const float*)d_in[5];
    const float* W2 = (const float*)d_in[6];
    const float* b2 = (const float*)d_in[7];
    const float* Wf = (const float*)d_in[8];
    const float* bf = (const float*)d_in[9];
    float* out = (float*)d_out;

    const int B = in_sizes[0] / E;   // 4096

    char* ws = (char*)d_ws;
    float*          Af     = (float*)(ws + WS_AF);
    float*          Cf     = (float*)(ws + WS_CF);
    unsigned short* W2f    = (unsigned short*)(ws + WS_W2F);
    float*          cq_all = (float*)(ws + WS_CQ);

    k0_pack<<<5, 256, 0, stream>>>(W1, W2, Af, Cf, W2f);
    k0_cq<<<(B * H1N + 255) / 256, 256, 0, stream>>>(q, W1, b1, cq_all, B);
    attn_main<<<B, 256, 0, stream>>>(q, k, v, mk, b2, Wf, bf,
                                     Af, Cf, W2f, cq_all, out);
}